// Round 2
// baseline (1804.450 us; speedup 1.0000x reference)
//
#include <hip/hip_runtime.h>

#define DIMD 512
#define KCB  1024
#define TT   2048
#define BB   16
#define NTOT (BB*TT)            // 32768
#define BN 64
#define BK 64
#define BD 32

#define OUT_IDX  (BB*DIMD*TT)          // 16777216
#define OUT_LOSS (OUT_IDX + BB*TT)     // 16809984

// ---------------- w2f[k] = fl32( sum_d fp64( fl32(cb^2) ) ) ----------------
__global__ __launch_bounds__(256) void w2_kernel(const float* __restrict__ cb,
                                                 float* __restrict__ w2) {
    int k = blockIdx.x * 256 + threadIdx.x;   // grid = 4 blocks
    const float* row = cb + (size_t)k * DIMD;
    double s = 0.0;
    #pragma unroll 8
    for (int j = 0; j < DIMD; ++j) {
        float v  = row[j];
        float vv = v * v;          // fp32 square, like np's z*z elementwise
        s += (double)vv;           // near-exact accumulate
    }
    w2[k] = (float)s;
}

// ---------------- argmin over k of fl32(fl32(z2 - 2*dot) + w2) ----------------
// Emulates np's fp32 rounding chain; dot accumulated in fp64 (near-exact).
__global__ __launch_bounds__(256) void argmin_kernel(
    const float* __restrict__ z, const float* __restrict__ cb,
    const float* __restrict__ w2, float* __restrict__ out_idx_f)
{
    __shared__ float zs[BD][BN];        // [32][64]
    __shared__ float ws[BD][BK + 4];    // [32][68]

    const int tid = threadIdx.x;
    const int n0  = blockIdx.x * BN;
    const int b   = n0 / TT;
    const int t0  = n0 % TT;
    const float* zb = z + (size_t)b * DIMD * TT + t0;

    const int j = tid & 15;    // col group (4 cols)
    const int i = tid >> 4;    // row group (4 rows)

    float bestv[4];
    int   besti[4];
    double z2a[4];
    float z2f[4];
    #pragma unroll
    for (int r = 0; r < 4; ++r) { bestv[r] = 3.4e38f; besti[r] = 0; z2a[r] = 0.0; }

    for (int k0 = 0; k0 < KCB; k0 += BK) {
        double acc[4][4];
        #pragma unroll
        for (int r = 0; r < 4; ++r)
            #pragma unroll
            for (int c = 0; c < 4; ++c) acc[r][c] = 0.0;

        for (int d0 = 0; d0 < DIMD; d0 += BD) {
            __syncthreads();
            // stage z tile: zs[d][n], coalesced float4
            #pragma unroll
            for (int q = 0; q < 2; ++q) {
                int p  = tid + 256 * q;
                int d  = p >> 4;
                int nf = (p & 15) << 2;
                *(float4*)&zs[d][nf] =
                    *(const float4*)(zb + (size_t)(d0 + d) * TT + nf);
            }
            // stage w tile transposed: ws[d][k]
            #pragma unroll
            for (int q = 0; q < 2; ++q) {
                int p  = tid + 256 * q;
                int kk = p >> 3;
                int d4 = (p & 7) << 2;
                float4 v = *(const float4*)(cb + (size_t)(k0 + kk) * DIMD + d0 + d4);
                ws[d4 + 0][kk] = v.x;
                ws[d4 + 1][kk] = v.y;
                ws[d4 + 2][kk] = v.z;
                ws[d4 + 3][kk] = v.w;
            }
            __syncthreads();
            for (int dd = 0; dd < BD; ++dd) {
                float4 zv = *(const float4*)&zs[dd][i << 2];
                float4 wv = *(const float4*)&ws[dd][j << 2];
                float zr[4] = {zv.x, zv.y, zv.z, zv.w};
                float wc[4] = {wv.x, wv.y, wv.z, wv.w};
                if (k0 == 0) {
                    // fused |z|^2: fp32 square (np-style), fp64 accumulate
                    #pragma unroll
                    for (int r = 0; r < 4; ++r) {
                        float zz = zr[r] * zr[r];
                        z2a[r] += (double)zz;
                    }
                }
                double zd[4], wd[4];
                #pragma unroll
                for (int r = 0; r < 4; ++r) zd[r] = (double)zr[r];
                #pragma unroll
                for (int c = 0; c < 4; ++c) wd[c] = (double)wc[c];
                #pragma unroll
                for (int r = 0; r < 4; ++r)
                    #pragma unroll
                    for (int c = 0; c < 4; ++c)
                        acc[r][c] = fma(zd[r], wd[c], acc[r][c]);
            }
        }
        if (k0 == 0) {
            #pragma unroll
            for (int r = 0; r < 4; ++r) z2f[r] = (float)z2a[r];
        }
        // np-emulated scores; strict < keeps smallest k on ties
        #pragma unroll
        for (int c = 0; c < 4; ++c) {
            int k = k0 + (j << 2) + c;
            float w2k = w2[k];
            #pragma unroll
            for (int r = 0; r < 4; ++r) {
                float dotf = (float)acc[r][c];        // fl32(near-exact dot)
                float t2   = z2f[r] - 2.0f * dotf;    // fl32(z2 - 2*dot), 2*dot exact
                float s    = t2 + w2k;                // fl32(t2 + w2)
                if (s < bestv[r]) { bestv[r] = s; besti[r] = k; }
            }
        }
    }

    // reduce across the 16 col-groups; ties -> smaller k
    #pragma unroll
    for (int m = 1; m < 16; m <<= 1) {
        #pragma unroll
        for (int r = 0; r < 4; ++r) {
            float ov = __shfl_xor(bestv[r], m, 64);
            int   oi = __shfl_xor(besti[r], m, 64);
            if (ov < bestv[r] || (ov == bestv[r] && oi < besti[r])) {
                bestv[r] = ov; besti[r] = oi;
            }
        }
    }
    if (j == 0) {
        #pragma unroll
        for (int r = 0; r < 4; ++r) {
            int n = n0 + (i << 2) + r;
            out_idx_f[n] = (float)besti[r];
        }
    }
}

// ---------------- gather z_q, write z_q_st, accumulate loss ----------------
__global__ __launch_bounds__(256) void gather_kernel(
    const float* __restrict__ z, const float* __restrict__ cb,
    const float* __restrict__ idx_f, float* __restrict__ out,
    float* __restrict__ loss)
{
    __shared__ float red[4];
    const size_t base = ((size_t)blockIdx.x * 256 + threadIdx.x) * 4;
    const int t  = (int)(base % TT);
    const int bd = (int)(base / TT);      // b*DIM + d
    const int d  = bd & (DIMD - 1);
    const int b  = bd / DIMD;

    float4 zv = *(const float4*)(z + base);
    const float* ip = idx_f + b * TT + t;
    int k0 = (int)(ip[0] + 0.5f);
    int k1 = (int)(ip[1] + 0.5f);
    int k2 = (int)(ip[2] + 0.5f);
    int k3 = (int)(ip[3] + 0.5f);
    float w0 = cb[(size_t)k0 * DIMD + d];
    float w1 = cb[(size_t)k1 * DIMD + d];
    float w2v = cb[(size_t)k2 * DIMD + d];
    float w3 = cb[(size_t)k3 * DIMD + d];

    float dx = w0 - zv.x, dy = w1 - zv.y, dz = w2v - zv.z, dw = w3 - zv.w;
    float4 ov = make_float4(zv.x + dx, zv.y + dy, zv.z + dz, zv.w + dw);
    *(float4*)(out + base) = ov;

    float part = dx * dx + dy * dy + dz * dz + dw * dw;
    #pragma unroll
    for (int m = 32; m >= 1; m >>= 1) part += __shfl_down(part, m, 64);
    const int lane = threadIdx.x & 63;
    const int wv   = threadIdx.x >> 6;
    if (lane == 0) red[wv] = part;
    __syncthreads();
    if (threadIdx.x == 0) {
        float tot = red[0] + red[1] + red[2] + red[3];
        atomicAdd(loss, tot * (1.25f / (float)(BB * DIMD * TT)));
    }
}

extern "C" void kernel_launch(void* const* d_in, const int* in_sizes, int n_in,
                              void* d_out, int out_size, void* d_ws, size_t ws_size,
                              hipStream_t stream) {
    const float* z  = (const float*)d_in[0];
    const float* cb = (const float*)d_in[1];
    float* out = (float*)d_out;
    float* w2  = (float*)d_ws;

    hipMemsetAsync(out + OUT_LOSS, 0, sizeof(float), stream);
    w2_kernel<<<KCB / 256, 256, 0, stream>>>(cb, w2);
    argmin_kernel<<<NTOT / BN, 256, 0, stream>>>(z, cb, w2, out + OUT_IDX);
    gather_kernel<<<(BB * DIMD * TT) / (256 * 4), 256, 0, stream>>>(
        z, cb, out + OUT_IDX, out, out + OUT_LOSS);
}

// Round 3
// 1613.924 us; speedup vs baseline: 1.1181x; 1.1181x over previous
//
#include <hip/hip_runtime.h>

typedef __bf16 bf16_t;
typedef __bf16 bf16x8 __attribute__((ext_vector_type(8)));
typedef float  f32x4  __attribute__((ext_vector_type(4)));

#define DIMD 512
#define KCB  1024
#define TT   2048
#define BB   16
#define NTOT (BB*TT)                   // 32768
#define OUT_IDX  (BB*DIMD*TT)          // 16777216
#define OUT_LOSS (OUT_IDX + NTOT)
#define TAU  2.5e-4f

// ---------------- w2[k] = fl32( fp64 sum of fl32(cb^2) ) ----------------
__global__ __launch_bounds__(256) void w2_kernel(const float* __restrict__ cb,
                                                 float* __restrict__ w2) {
    int k = blockIdx.x * 256 + threadIdx.x;
    const float* row = cb + (size_t)k * DIMD;
    double s = 0.0;
    for (int j = 0; j < DIMD; ++j) {
        float v  = row[j];
        float vv = v * v;
        s += (double)vv;
    }
    w2[k] = (float)s;
}

// ---------------- split codebook into bf16 hi/lo ----------------
__global__ __launch_bounds__(256) void wsplit_kernel(const float* __restrict__ cb,
                                                     bf16_t* __restrict__ wh,
                                                     bf16_t* __restrict__ wl) {
    int i = blockIdx.x * 256 + threadIdx.x;   // grid = 1024*512/256 = 2048
    float v = cb[i];
    bf16_t h = (bf16_t)v;
    wh[i] = h;
    wl[i] = (bf16_t)(v - (float)h);
}

// ---------------- fast argmin: split-bf16 MFMA + margin flagging ----------------
// Block = 64 tokens (4 waves x 16). A = tokens (register-resident frags),
// B = codebook (hi/lo from L2). Score = w2[k] - 2*dot (z^2 dropped: row-const).
__global__ __launch_bounds__(256, 2) void fast_argmin_kernel(
    const float* __restrict__ z, const bf16_t* __restrict__ wh,
    const bf16_t* __restrict__ wl, const float* __restrict__ w2,
    float* __restrict__ out_idx_f, int* __restrict__ cnt, int* __restrict__ list)
{
    const int tid  = threadIdx.x;
    const int wave = tid >> 6;
    const int lane = tid & 63;
    const int m    = lane & 15;    // A-row (token) for frags; B-col (cb) for scores
    const int quad = lane >> 4;

    // ---- load A fragments once: 16 d-chunks x (hi,lo) ----
    const int n = blockIdx.x * 64 + wave * 16 + m;
    const int b = n >> 11, t = n & 2047;
    const float* zbase = z + (size_t)b * DIMD * TT + t;

    bf16x8 Ah[16], Al[16];
    #pragma unroll
    for (int q = 0; q < 16; ++q) {
        #pragma unroll
        for (int j = 0; j < 8; ++j) {
            int d = q * 32 + quad * 8 + j;
            float v = zbase[(size_t)d * TT];
            bf16_t h = (bf16_t)v;
            Ah[q][j] = h;
            Al[q][j] = (bf16_t)(v - (float)h);
        }
    }

    float b1[4], b2[4];
    int   i1[4];
    #pragma unroll
    for (int r = 0; r < 4; ++r) { b1[r] = 3.4e38f; b2[r] = 3.4e38f; i1[r] = 0; }

    for (int k0 = 0; k0 < KCB; k0 += 64) {
        f32x4 acc[4] = {};
        #pragma unroll
        for (int q = 0; q < 16; ++q) {
            #pragma unroll
            for (int nt = 0; nt < 4; ++nt) {
                const size_t off = (size_t)(k0 + nt * 16 + m) * DIMD + q * 32 + quad * 8;
                bf16x8 bh = *(const bf16x8*)(wh + off);
                bf16x8 bl = *(const bf16x8*)(wl + off);
                acc[nt] = __builtin_amdgcn_mfma_f32_16x16x32_bf16(Ah[q], bh, acc[nt], 0, 0, 0);
                acc[nt] = __builtin_amdgcn_mfma_f32_16x16x32_bf16(Al[q], bh, acc[nt], 0, 0, 0);
                acc[nt] = __builtin_amdgcn_mfma_f32_16x16x32_bf16(Ah[q], bl, acc[nt], 0, 0, 0);
            }
        }
        #pragma unroll
        for (int nt = 0; nt < 4; ++nt) {
            int   k   = k0 + nt * 16 + m;
            float w2v = w2[k];
            #pragma unroll
            for (int r = 0; r < 4; ++r) {
                float s = fmaf(-2.0f, acc[nt][r], w2v);
                if (s < b1[r]) { b2[r] = b1[r]; b1[r] = s; i1[r] = k; }
                else if (s < b2[r]) b2[r] = s;
            }
        }
    }

    // merge (best1, idx1, best2) across the 16 lanes of each quad
    #pragma unroll
    for (int msk = 1; msk < 16; msk <<= 1) {
        #pragma unroll
        for (int r = 0; r < 4; ++r) {
            float ov1 = __shfl_xor(b1[r], msk, 64);
            int   oi1 = __shfl_xor(i1[r], msk, 64);
            float ov2 = __shfl_xor(b2[r], msk, 64);
            if (ov1 < b1[r] || (ov1 == b1[r] && oi1 < i1[r])) {
                b2[r] = fminf(b1[r], ov2);
                b1[r] = ov1; i1[r] = oi1;
            } else {
                b2[r] = fminf(b2[r], ov1);
            }
        }
    }
    if (m == 0) {
        #pragma unroll
        for (int r = 0; r < 4; ++r) {
            int tok = blockIdx.x * 64 + wave * 16 + quad * 4 + r;
            out_idx_f[tok] = (float)i1[r];
            if (b2[r] - b1[r] <= TAU) {
                int p = atomicAdd(cnt, 1);
                list[p] = tok;
            }
        }
    }
}

// ---------------- exact np-emulating recheck of flagged rows ----------------
__global__ __launch_bounds__(256) void recheck_kernel(
    const float* __restrict__ z, const float* __restrict__ cb,
    const float* __restrict__ w2, const int* __restrict__ cnt,
    const int* __restrict__ list, float* __restrict__ out_idx_f)
{
    __shared__ float  zrow[DIMD];
    __shared__ double zred[4];
    __shared__ float  rv[4];
    __shared__ int    ri[4];

    const int total = *cnt;
    for (int it = blockIdx.x; it < total; it += gridDim.x) {
        __syncthreads();   // protect shared reuse across iterations
        int tok = list[it];
        int b = tok >> 11, t = tok & 2047;
        const float* zb = z + (size_t)b * DIMD * TT + t;

        double zp = 0.0;
        for (int d = threadIdx.x; d < DIMD; d += 256) {
            float v = zb[(size_t)d * TT];
            zrow[d] = v;
            float vv = v * v;
            zp += (double)vv;
        }
        #pragma unroll
        for (int msk = 1; msk < 64; msk <<= 1) zp += __shfl_xor(zp, msk, 64);
        if ((threadIdx.x & 63) == 0) zred[threadIdx.x >> 6] = zp;
        __syncthreads();
        float z2f = (float)(zred[0] + zred[1] + zred[2] + zred[3]);

        double acc[4] = {0.0, 0.0, 0.0, 0.0};
        for (int d = 0; d < DIMD; d += 4) {
            float4 zv = *(const float4*)&zrow[d];
            #pragma unroll
            for (int j = 0; j < 4; ++j) {
                float4 wv = *(const float4*)(cb + (size_t)(threadIdx.x + 256 * j) * DIMD + d);
                acc[j] = fma((double)zv.x, (double)wv.x, acc[j]);
                acc[j] = fma((double)zv.y, (double)wv.y, acc[j]);
                acc[j] = fma((double)zv.z, (double)wv.z, acc[j]);
                acc[j] = fma((double)zv.w, (double)wv.w, acc[j]);
            }
        }
        float bv = 3.4e38f; int bi = 0;
        #pragma unroll
        for (int j = 0; j < 4; ++j) {
            int k = threadIdx.x + 256 * j;
            float dotf = (float)acc[j];
            float t2   = z2f - 2.0f * dotf;   // np chain: fl(z2 - 2*dot)
            float s    = t2 + w2[k];          // fl(t2 + w2)
            if (s < bv) { bv = s; bi = k; }   // k ascending -> first-min
        }
        #pragma unroll
        for (int msk = 1; msk < 64; msk <<= 1) {
            float ov = __shfl_xor(bv, msk, 64);
            int   oi = __shfl_xor(bi, msk, 64);
            if (ov < bv || (ov == bv && oi < bi)) { bv = ov; bi = oi; }
        }
        if ((threadIdx.x & 63) == 0) { rv[threadIdx.x >> 6] = bv; ri[threadIdx.x >> 6] = bi; }
        __syncthreads();
        if (threadIdx.x == 0) {
            #pragma unroll
            for (int w = 1; w < 4; ++w)
                if (rv[w] < bv || (rv[w] == bv && ri[w] < bi)) { bv = rv[w]; bi = ri[w]; }
            out_idx_f[tok] = (float)bi;
        }
    }
}

// ---------------- gather z_q, write z_q_st, accumulate loss ----------------
__global__ __launch_bounds__(256) void gather_kernel(
    const float* __restrict__ z, const float* __restrict__ cb,
    const float* __restrict__ idx_f, float* __restrict__ out,
    float* __restrict__ loss)
{
    __shared__ float red[4];
    const size_t base = ((size_t)blockIdx.x * 256 + threadIdx.x) * 4;
    const int t  = (int)(base % TT);
    const int bd = (int)(base / TT);
    const int d  = bd & (DIMD - 1);
    const int b  = bd / DIMD;

    float4 zv = *(const float4*)(z + base);
    const float* ip = idx_f + b * TT + t;
    int k0 = (int)(ip[0] + 0.5f);
    int k1 = (int)(ip[1] + 0.5f);
    int k2 = (int)(ip[2] + 0.5f);
    int k3 = (int)(ip[3] + 0.5f);
    float w0  = cb[(size_t)k0 * DIMD + d];
    float w1  = cb[(size_t)k1 * DIMD + d];
    float w2v = cb[(size_t)k2 * DIMD + d];
    float w3  = cb[(size_t)k3 * DIMD + d];

    float dx = w0 - zv.x, dy = w1 - zv.y, dz = w2v - zv.z, dw = w3 - zv.w;
    float4 ov = make_float4(zv.x + dx, zv.y + dy, zv.z + dz, zv.w + dw);
    *(float4*)(out + base) = ov;

    float part = dx * dx + dy * dy + dz * dz + dw * dw;
    #pragma unroll
    for (int msk = 32; msk >= 1; msk >>= 1) part += __shfl_down(part, msk, 64);
    const int lane = threadIdx.x & 63;
    const int wv   = threadIdx.x >> 6;
    if (lane == 0) red[wv] = part;
    __syncthreads();
    if (threadIdx.x == 0) {
        float tot = red[0] + red[1] + red[2] + red[3];
        atomicAdd(loss, tot * (1.25f / (float)(BB * DIMD * TT)));
    }
}

extern "C" void kernel_launch(void* const* d_in, const int* in_sizes, int n_in,
                              void* d_out, int out_size, void* d_ws, size_t ws_size,
                              hipStream_t stream) {
    const float* z  = (const float*)d_in[0];
    const float* cb = (const float*)d_in[1];
    float* out = (float*)d_out;

    char* wsb = (char*)d_ws;
    bf16_t* wh  = (bf16_t*)wsb;                        // 1 MB
    bf16_t* wl  = (bf16_t*)(wsb + (1 << 20));          // 1 MB
    float*  w2  = (float*)(wsb + (2 << 20));           // 4 KB
    int*    cnt = (int*)(wsb + (2 << 20) + 4096);
    int*    list= (int*)(wsb + (2 << 20) + 8192);      // 128 KB

    hipMemsetAsync(out + OUT_LOSS, 0, sizeof(float), stream);
    hipMemsetAsync(cnt, 0, sizeof(int), stream);
    w2_kernel<<<KCB / 256, 256, 0, stream>>>(cb, w2);
    wsplit_kernel<<<KCB * DIMD / 256, 256, 0, stream>>>(cb, wh, wl);
    fast_argmin_kernel<<<NTOT / 64, 256, 0, stream>>>(z, wh, wl, w2,
                                                      out + OUT_IDX, cnt, list);
    recheck_kernel<<<512, 256, 0, stream>>>(z, cb, w2, cnt, list, out + OUT_IDX);
    gather_kernel<<<(BB * DIMD * TT) / (256 * 4), 256, 0, stream>>>(
        z, cb, out + OUT_IDX, out, out + OUT_LOSS);
}

// Round 4
// 700.520 us; speedup vs baseline: 2.5759x; 2.3039x over previous
//
#include <hip/hip_runtime.h>

typedef __bf16 bf16_t;
typedef __bf16 bf16x8 __attribute__((ext_vector_type(8)));
typedef float  f32x4  __attribute__((ext_vector_type(4)));

#define DIMD 512
#define KCB  1024
#define TT   2048
#define BB   16
#define NTOT (BB*TT)                   // 32768
#define OUT_IDX  (BB*DIMD*TT)          // 16777216
#define OUT_LOSS (OUT_IDX + NTOT)
#define TAU 2.0e-4f

__device__ __forceinline__ void gll16(const bf16_t* g, bf16_t* l) {
    __builtin_amdgcn_global_load_lds(
        (const __attribute__((address_space(1))) unsigned int*)g,
        (__attribute__((address_space(3))) unsigned int*)l, 16, 0, 0);
}

// ---------------- w2[k] = fl32( fp64 sum of fl32(cb^2) ) ----------------
__global__ __launch_bounds__(256) void w2_kernel(const float* __restrict__ cb,
                                                 float* __restrict__ w2) {
    int k = blockIdx.x * 256 + threadIdx.x;
    const float* row = cb + (size_t)k * DIMD;
    double s = 0.0;
    for (int j = 0; j < DIMD; ++j) {
        float v  = row[j];
        float vv = v * v;
        s += (double)vv;
    }
    w2[k] = (float)s;
}

// ---------------- split codebook into bf16 hi/lo ----------------
__global__ __launch_bounds__(256) void wsplit_kernel(const float* __restrict__ cb,
                                                     bf16_t* __restrict__ wh,
                                                     bf16_t* __restrict__ wl) {
    int i = blockIdx.x * 256 + threadIdx.x;   // grid = 2048
    float v = cb[i];
    bf16_t h = (bf16_t)v;
    wh[i] = h;
    wl[i] = (bf16_t)(v - (float)h);
}

// ---------------- transpose z -> token-major bf16 hi/lo ----------------
// block: 64 tokens x 128 d; wave w covers 32 d. Reads coalesced (256B/d-row).
__global__ __launch_bounds__(256) void tsplit_kernel(const float* __restrict__ z,
                                                     bf16_t* __restrict__ zh,
                                                     bf16_t* __restrict__ zl) {
    const int tid = threadIdx.x;
    const int tok = (blockIdx.x >> 2) * 64 + (tid & 63);
    const int d0  = (blockIdx.x & 3) * 128 + (tid >> 6) * 32;
    const int b = tok >> 11, t = tok & 2047;
    const float* src = z + (size_t)b * DIMD * TT + t;
    bf16x8 hh[4], ll[4];
    #pragma unroll
    for (int c = 0; c < 4; ++c) {
        #pragma unroll
        for (int j = 0; j < 8; ++j) {
            float v = src[(size_t)(d0 + c * 8 + j) * TT];
            bf16_t h = (bf16_t)v;
            hh[c][j] = h;
            ll[c][j] = (bf16_t)(v - (float)h);
        }
    }
    const size_t ob = (size_t)tok * DIMD + d0;
    #pragma unroll
    for (int c = 0; c < 4; ++c) {
        *(bf16x8*)(zh + ob + c * 8) = hh[c];
        *(bf16x8*)(zl + ob + c * 8) = ll[c];
    }
}

// ---------------- fast argmin: LDS-tiled split-bf16 MFMA GEMM ----------------
// Block: 32 tokens x all 1024 codes (8 tiles of 128). 4 waves: wave = 16 tok x 64 codes.
// LDS 40KB -> 4 blocks/CU, 16 waves/CU.
__global__ __launch_bounds__(256, 4) void fast_kernel(
    const bf16_t* __restrict__ zh, const bf16_t* __restrict__ zl,
    const bf16_t* __restrict__ wh, const bf16_t* __restrict__ wl,
    const float* __restrict__ w2, float* __restrict__ out_idx_f,
    int* __restrict__ cnt, int* __restrict__ list)
{
    __shared__ __align__(16) bf16_t Ah[32 * 64];
    __shared__ __align__(16) bf16_t Al[32 * 64];
    __shared__ __align__(16) bf16_t Bh[128 * 64];
    __shared__ __align__(16) bf16_t Bl[128 * 64];

    const int tid  = threadIdx.x;
    const int wave = tid >> 6;
    const int lane = tid & 63;
    const int m    = lane & 15;
    const int quad = lane >> 4;
    const int tok0 = blockIdx.x * 32;
    const int ht   = wave & 1;     // token half (16)
    const int hc   = wave >> 1;    // code half (64)

    float b1[4], b2[4]; int i1[4];
    #pragma unroll
    for (int r = 0; r < 4; ++r) { b1[r] = 3.4e38f; b2[r] = 3.4e38f; i1[r] = 0; }

    // staging addresses (constant parts)
    const size_t ga_row = (size_t)(tok0 + (tid >> 3)) * DIMD + (tid & 7) * 8;

    for (int ct = 0; ct < 8; ++ct) {
        f32x4 acc[4] = {};
        for (int d0 = 0; d0 < DIMD; d0 += 64) {
            __syncthreads();
            // A: 32x64 (512 16B-chunks = 2 batches incl hi/lo)
            gll16(zh + ga_row + d0, Ah + tid * 8);
            gll16(zl + ga_row + d0, Al + tid * 8);
            // B: 128x64 (1024 chunks -> 4 batches) x hi/lo
            #pragma unroll
            for (int q = 0; q < 4; ++q) {
                const int c = q * 256 + tid;
                const size_t g = (size_t)(ct * 128 + (c >> 3)) * DIMD + d0 + (c & 7) * 8;
                gll16(wh + g, Bh + c * 8);
                gll16(wl + g, Bl + c * 8);
            }
            __syncthreads();
            #pragma unroll
            for (int kh = 0; kh < 2; ++kh) {
                const int ao = (ht * 16 + m) * 64 + kh * 32 + quad * 8;
                bf16x8 ah = *(const bf16x8*)(Ah + ao);
                bf16x8 al = *(const bf16x8*)(Al + ao);
                #pragma unroll
                for (int fc = 0; fc < 4; ++fc) {
                    const int bo = (hc * 64 + fc * 16 + m) * 64 + kh * 32 + quad * 8;
                    bf16x8 bh = *(const bf16x8*)(Bh + bo);
                    bf16x8 bl = *(const bf16x8*)(Bl + bo);
                    acc[fc] = __builtin_amdgcn_mfma_f32_16x16x32_bf16(ah, bh, acc[fc], 0, 0, 0);
                    acc[fc] = __builtin_amdgcn_mfma_f32_16x16x32_bf16(al, bh, acc[fc], 0, 0, 0);
                    acc[fc] = __builtin_amdgcn_mfma_f32_16x16x32_bf16(ah, bl, acc[fc], 0, 0, 0);
                }
            }
        }
        // scores for this code-tile; merge into running best1/best2
        #pragma unroll
        for (int r = 0; r < 4; ++r) {
            float t1 = 3.4e38f, t2 = 3.4e38f; int ti = 0;
            #pragma unroll
            for (int fc = 0; fc < 4; ++fc) {
                int k = ct * 128 + hc * 64 + fc * 16 + m;
                float s = fmaf(-2.0f, acc[fc][r], w2[k]);
                if (s < t1) { t2 = t1; t1 = s; ti = k; }
                else if (s < t2) t2 = s;
            }
            #pragma unroll
            for (int msk = 1; msk < 16; msk <<= 1) {
                float o1 = __shfl_xor(t1, msk, 64);
                int   oi = __shfl_xor(ti, msk, 64);
                float o2 = __shfl_xor(t2, msk, 64);
                if (o1 < t1 || (o1 == t1 && oi < ti)) { t2 = fminf(t1, o2); t1 = o1; ti = oi; }
                else t2 = fminf(t2, o1);
            }
            if (t1 < b1[r] || (t1 == b1[r] && ti < i1[r])) {
                b2[r] = fminf(b1[r], t2); b1[r] = t1; i1[r] = ti;
            } else {
                b2[r] = fminf(b2[r], t1);
            }
        }
    }

    // merge code-halves: waves 2,3 publish; waves 0,1 combine + write
    __syncthreads();
    float* mb1 = (float*)Ah;           // reuse LDS (384B < 4KB)
    float* mb2 = mb1 + 32;
    int*   mi  = (int*)(mb1 + 64);
    if (wave >= 2 && m == 0) {
        #pragma unroll
        for (int r = 0; r < 4; ++r) {
            int tl = ht * 16 + quad * 4 + r;
            mb1[tl] = b1[r]; mb2[tl] = b2[r]; mi[tl] = i1[r];
        }
    }
    __syncthreads();
    if (wave < 2 && m == 0) {
        #pragma unroll
        for (int r = 0; r < 4; ++r) {
            int tl = ht * 16 + quad * 4 + r;
            float o1 = mb1[tl], o2 = mb2[tl]; int oi = mi[tl];
            if (o1 < b1[r] || (o1 == b1[r] && oi < i1[r])) {
                b2[r] = fminf(b1[r], o2); b1[r] = o1; i1[r] = oi;
            } else {
                b2[r] = fminf(b2[r], o1);
            }
            int tok = tok0 + tl;
            out_idx_f[tok] = (float)i1[r];
            if (b2[r] - b1[r] <= TAU) {
                int p = atomicAdd(cnt, 1);
                list[p] = tok;
            }
        }
    }
}

// ---------------- exact np-emulating recheck, 4 rows per block ----------------
__global__ __launch_bounds__(256) void recheck_kernel(
    const float* __restrict__ z, const float* __restrict__ cb,
    const float* __restrict__ w2, const int* __restrict__ cnt,
    const int* __restrict__ list, float* __restrict__ out_idx_f)
{
    __shared__ float zrow[4][DIMD];
    __shared__ float z2s[4];
    __shared__ float rv[4][4];
    __shared__ int   ri[4][4];

    const int tid  = threadIdx.x;
    const int wave = tid >> 6;
    const int lane = tid & 63;
    const int total = *cnt;
    const int ngrp = (total + 3) >> 2;

    for (int g = blockIdx.x; g < ngrp; g += gridDim.x) {
        __syncthreads();
        const int nrows = min(4, total - g * 4);
        // wave w loads row w (strided gather), fp64 |z|^2
        {
            int idx = g * 4 + wave;
            int tok = (idx < total) ? list[idx] : list[g * 4];
            int b = tok >> 11, t = tok & 2047;
            const float* zb = z + (size_t)b * DIMD * TT + t;
            double zp = 0.0;
            #pragma unroll
            for (int j = 0; j < 8; ++j) {
                int d = lane + 64 * j;
                float v = zb[(size_t)d * TT];
                zrow[wave][d] = v;
                float vv = v * v;
                zp += (double)vv;
            }
            #pragma unroll
            for (int msk = 1; msk < 64; msk <<= 1) zp += __shfl_xor(zp, msk, 64);
            if (lane == 0) z2s[wave] = (float)zp;
        }
        __syncthreads();

        // thread: 4 codes (tid + 256*jc) x 4 rows, fp64 dots; z broadcast from LDS
        double acc[4][4];
        #pragma unroll
        for (int jc = 0; jc < 4; ++jc)
            #pragma unroll
            for (int r = 0; r < 4; ++r) acc[jc][r] = 0.0;

        for (int d0 = 0; d0 < DIMD; d0 += 4) {
            float4 zv[4];
            #pragma unroll
            for (int r = 0; r < 4; ++r) zv[r] = *(const float4*)&zrow[r][d0];
            #pragma unroll
            for (int jc = 0; jc < 4; ++jc) {
                float4 wv = *(const float4*)(cb + (size_t)(tid + 256 * jc) * DIMD + d0);
                #pragma unroll
                for (int r = 0; r < 4; ++r) {
                    acc[jc][r] = fma((double)zv[r].x, (double)wv.x, acc[jc][r]);
                    acc[jc][r] = fma((double)zv[r].y, (double)wv.y, acc[jc][r]);
                    acc[jc][r] = fma((double)zv[r].z, (double)wv.z, acc[jc][r]);
                    acc[jc][r] = fma((double)zv[r].w, (double)wv.w, acc[jc][r]);
                }
            }
        }

        float bv[4]; int bi[4];
        #pragma unroll
        for (int r = 0; r < 4; ++r) { bv[r] = 3.4e38f; bi[r] = 0; }
        #pragma unroll
        for (int jc = 0; jc < 4; ++jc) {
            int k = tid + 256 * jc;
            float w2k = w2[k];
            #pragma unroll
            for (int r = 0; r < 4; ++r) {
                float dotf = (float)acc[jc][r];
                float t2   = z2s[r] - 2.0f * dotf;   // np chain: fl(z2 - 2*dot)
                float s    = t2 + w2k;               // fl(t2 + w2)
                if (s < bv[r] || (s == bv[r] && k < bi[r])) { bv[r] = s; bi[r] = k; }
            }
        }
        #pragma unroll
        for (int msk = 1; msk < 64; msk <<= 1) {
            #pragma unroll
            for (int r = 0; r < 4; ++r) {
                float ov = __shfl_xor(bv[r], msk, 64);
                int   oi = __shfl_xor(bi[r], msk, 64);
                if (ov < bv[r] || (ov == bv[r] && oi < bi[r])) { bv[r] = ov; bi[r] = oi; }
            }
        }
        if (lane == 0) {
            #pragma unroll
            for (int r = 0; r < 4; ++r) { rv[wave][r] = bv[r]; ri[wave][r] = bi[r]; }
        }
        __syncthreads();
        if (tid < nrows) {
            float v = rv[0][tid]; int k = ri[0][tid];
            #pragma unroll
            for (int w = 1; w < 4; ++w) {
                if (rv[w][tid] < v || (rv[w][tid] == v && ri[w][tid] < k)) {
                    v = rv[w][tid]; k = ri[w][tid];
                }
            }
            out_idx_f[list[g * 4 + tid]] = (float)k;
        }
    }
}

// ---------------- gather z_q, write z_q_st, accumulate loss ----------------
__global__ __launch_bounds__(256) void gather_kernel(
    const float* __restrict__ z, const float* __restrict__ cb,
    const float* __restrict__ idx_f, float* __restrict__ out,
    float* __restrict__ loss)
{
    __shared__ float red[4];
    const size_t base = ((size_t)blockIdx.x * 256 + threadIdx.x) * 4;
    const int t  = (int)(base % TT);
    const int bd = (int)(base / TT);
    const int d  = bd & (DIMD - 1);
    const int b  = bd / DIMD;

    float4 zv = *(const float4*)(z + base);
    const float* ip = idx_f + b * TT + t;
    int k0 = (int)(ip[0] + 0.5f);
    int k1 = (int)(ip[1] + 0.5f);
    int k2 = (int)(ip[2] + 0.5f);
    int k3 = (int)(ip[3] + 0.5f);
    float w0  = cb[(size_t)k0 * DIMD + d];
    float w1  = cb[(size_t)k1 * DIMD + d];
    float w2v = cb[(size_t)k2 * DIMD + d];
    float w3  = cb[(size_t)k3 * DIMD + d];

    float dx = w0 - zv.x, dy = w1 - zv.y, dz = w2v - zv.z, dw = w3 - zv.w;
    float4 ov = make_float4(zv.x + dx, zv.y + dy, zv.z + dz, zv.w + dw);
    *(float4*)(out + base) = ov;

    float part = dx * dx + dy * dy + dz * dz + dw * dw;
    #pragma unroll
    for (int msk = 32; msk >= 1; msk >>= 1) part += __shfl_down(part, msk, 64);
    const int lane = threadIdx.x & 63;
    const int wv   = threadIdx.x >> 6;
    if (lane == 0) red[wv] = part;
    __syncthreads();
    if (threadIdx.x == 0) {
        float tot = red[0] + red[1] + red[2] + red[3];
        atomicAdd(loss, tot * (1.25f / (float)(BB * DIMD * TT)));
    }
}

extern "C" void kernel_launch(void* const* d_in, const int* in_sizes, int n_in,
                              void* d_out, int out_size, void* d_ws, size_t ws_size,
                              hipStream_t stream) {
    const float* z  = (const float*)d_in[0];
    const float* cb = (const float*)d_in[1];
    float* out = (float*)d_out;

    // zT hi/lo scratch lives in the z_q_st output region (exactly 67.1 MB),
    // consumed by fast_kernel, then overwritten by gather_kernel.
    bf16_t* zh = (bf16_t*)out;
    bf16_t* zl = zh + (size_t)NTOT * DIMD;

    char* wsb = (char*)d_ws;                      // ~2.15 MB total (round-3-proven)
    bf16_t* wh  = (bf16_t*)wsb;                   // 1 MB
    bf16_t* wl  = (bf16_t*)(wsb + (1 << 20));     // 1 MB
    float*  w2  = (float*)(wsb + (2 << 20));      // 4 KB
    int*    cnt = (int*)(wsb + (2 << 20) + 4096);
    int*    list= (int*)(wsb + (2 << 20) + 8192); // 132 KB

    hipMemsetAsync(out + OUT_LOSS, 0, sizeof(float), stream);
    hipMemsetAsync(cnt, 0, sizeof(int), stream);
    w2_kernel<<<KCB / 256, 256, 0, stream>>>(cb, w2);
    wsplit_kernel<<<KCB * DIMD / 256, 256, 0, stream>>>(cb, wh, wl);
    tsplit_kernel<<<(NTOT / 64) * 4, 256, 0, stream>>>(z, zh, zl);
    fast_kernel<<<NTOT / 32, 256, 0, stream>>>(zh, zl, wh, wl, w2,
                                               out + OUT_IDX, cnt, list);
    recheck_kernel<<<512, 256, 0, stream>>>(z, cb, w2, cnt, list, out + OUT_IDX);
    gather_kernel<<<(BB * DIMD * TT) / (256 * 4), 256, 0, stream>>>(
        z, cb, out + OUT_IDX, out, out + OUT_LOSS);
}

// Round 5
// 638.654 us; speedup vs baseline: 2.8254x; 1.0969x over previous
//
#include <hip/hip_runtime.h>

typedef _Float16 f16_t;
typedef _Float16 f16x8 __attribute__((ext_vector_type(8)));
typedef float    f32x4 __attribute__((ext_vector_type(4)));

#define DIMD 512
#define KCB  1024
#define TT   2048
#define BB   16
#define NTOT (BB*TT)                   // 32768
#define OUT_IDX  (BB*DIMD*TT)          // 16777216
#define OUT_LOSS (OUT_IDX + NTOT)
#define TAU 3.0e-4f
// score = w2[k] - 2*dot; fast dot computed on (z, 1024*w) -> scale back by 2^-10
#define NEG2_SCALE (-0.001953125f)     // -2/1024, exact

__device__ __forceinline__ void gll16(const f16_t* g, f16_t* l) {
    __builtin_amdgcn_global_load_lds(
        (const __attribute__((address_space(1))) unsigned int*)g,
        (__attribute__((address_space(3))) unsigned int*)l, 16, 0, 0);
}

// ---------- prep: wf16[k][d] = f16(1024*cb), w2[k] = fl32(fp64 sum fl32(cb^2)) ----------
// grid 256, block 256: wave per codebook row.
__global__ __launch_bounds__(256) void prep_kernel(const float* __restrict__ cb,
                                                   f16_t* __restrict__ wf,
                                                   float* __restrict__ w2) {
    const int wave = threadIdx.x >> 6, lane = threadIdx.x & 63;
    const int row  = blockIdx.x * 4 + wave;
    const float* src = cb + (size_t)row * DIMD + lane * 8;
    float4 v0 = *(const float4*)(src);
    float4 v1 = *(const float4*)(src + 4);
    f16x8 o;
    o[0] = (f16_t)(v0.x * 1024.f); o[1] = (f16_t)(v0.y * 1024.f);
    o[2] = (f16_t)(v0.z * 1024.f); o[3] = (f16_t)(v0.w * 1024.f);
    o[4] = (f16_t)(v1.x * 1024.f); o[5] = (f16_t)(v1.y * 1024.f);
    o[6] = (f16_t)(v1.z * 1024.f); o[7] = (f16_t)(v1.w * 1024.f);
    *(f16x8*)(wf + (size_t)row * DIMD + lane * 8) = o;
    // np-style: square in fp32, accumulate near-exact (fp64)
    float s0 = v0.x * v0.x, s1 = v0.y * v0.y, s2 = v0.z * v0.z, s3 = v0.w * v0.w;
    float s4 = v1.x * v1.x, s5 = v1.y * v1.y, s6 = v1.z * v1.z, s7 = v1.w * v1.w;
    double s = (double)s0 + (double)s1 + (double)s2 + (double)s3 +
               (double)s4 + (double)s5 + (double)s6 + (double)s7;
    #pragma unroll
    for (int m = 1; m < 64; m <<= 1) s += __shfl_xor(s, m, 64);
    if (lane == 0) w2[row] = (float)s;
}

// ---------- transpose z -> token-major fp16 ----------
__global__ __launch_bounds__(256) void tsplit_kernel(const float* __restrict__ z,
                                                     f16_t* __restrict__ zf) {
    const int tid = threadIdx.x;
    const int tok = (blockIdx.x >> 2) * 64 + (tid & 63);
    const int d0  = (blockIdx.x & 3) * 128 + (tid >> 6) * 32;
    const int b = tok >> 11, t = tok & 2047;
    const float* src = z + (size_t)b * DIMD * TT + t;
    f16x8 o[4];
    #pragma unroll
    for (int c = 0; c < 4; ++c)
        #pragma unroll
        for (int j = 0; j < 8; ++j)
            o[c][j] = (f16_t)src[(size_t)(d0 + c * 8 + j) * TT];
    const size_t ob = (size_t)tok * DIMD + d0;
    #pragma unroll
    for (int c = 0; c < 4; ++c)
        *(f16x8*)(zf + ob + c * 8) = o[c];
}

// ---------- fast argmin: fp16 MFMA, XOR-swizzled LDS, 64tok x 1024codes ----------
// grid 512 blocks; 4 waves: wave = (tok-half of 32) x (code-half of 64).
// LDS 24KB, ~115 VGPR -> 4 blocks/CU.
__global__ __launch_bounds__(256, 4) void fast_kernel(
    const f16_t* __restrict__ zf, const f16_t* __restrict__ wf,
    const float* __restrict__ w2, float* __restrict__ out_idx_f,
    int* __restrict__ cnt, int* __restrict__ list)
{
    __shared__ __align__(16) f16_t As[64 * 64];    // 8KB  [tok][d] swizzled
    __shared__ __align__(16) f16_t Bs[128 * 64];   // 16KB [code][d] swizzled

    const int tid  = threadIdx.x;
    const int wave = tid >> 6;
    const int lane = tid & 63;
    const int m    = lane & 15;
    const int quad = lane >> 4;
    const int rh   = wave & 1;     // token half (32)
    const int chh  = wave >> 1;    // code half (64)
    const int tok0 = blockIdx.x * 64;

    // staging source/dest precompute. slot s -> row=s>>3, p=s&7; global chunk = p^(row&7)
    const f16_t* gA[2]; f16_t* lA[2];
    const f16_t* gB[4]; f16_t* lB[4];
    #pragma unroll
    for (int q = 0; q < 2; ++q) {
        int s = q * 256 + tid, row = s >> 3, p = s & 7, gc = p ^ (row & 7);
        gA[q] = zf + (size_t)(tok0 + row) * DIMD + gc * 8;
        lA[q] = As + s * 8;
    }
    #pragma unroll
    for (int q = 0; q < 4; ++q) {
        int s = q * 256 + tid, row = s >> 3, p = s & 7, gc = p ^ (row & 7);
        gB[q] = wf + (size_t)row * DIMD + gc * 8;
        lB[q] = Bs + s * 8;
    }

    float b1[8], b2[8]; int i1[8];
    #pragma unroll
    for (int r = 0; r < 8; ++r) { b1[r] = 3.4e38f; b2[r] = 3.4e38f; i1[r] = 0; }

    const int xorm = m & 7;
    for (int ct = 0; ct < 8; ++ct) {
        float w2c[4];
        #pragma unroll
        for (int nt = 0; nt < 4; ++nt)
            w2c[nt] = w2[ct * 128 + chh * 64 + nt * 16 + m];

        f32x4 acc[2][4] = {};
        const size_t ctoff = (size_t)ct * 128 * DIMD;
        for (int d0 = 0; d0 < DIMD; d0 += 64) {
            __syncthreads();
            #pragma unroll
            for (int q = 0; q < 2; ++q) gll16(gA[q] + d0, lA[q]);
            #pragma unroll
            for (int q = 0; q < 4; ++q) gll16(gB[q] + ctoff + d0, lB[q]);
            __syncthreads();
            #pragma unroll
            for (int kh = 0; kh < 2; ++kh) {
                const int csw = ((kh * 4 + quad) ^ xorm) * 8;
                f16x8 af[2], bf[4];
                #pragma unroll
                for (int mt = 0; mt < 2; ++mt)
                    af[mt] = *(const f16x8*)(As + (rh * 32 + mt * 16 + m) * 64 + csw);
                #pragma unroll
                for (int nt = 0; nt < 4; ++nt)
                    bf[nt] = *(const f16x8*)(Bs + (chh * 64 + nt * 16 + m) * 64 + csw);
                #pragma unroll
                for (int mt = 0; mt < 2; ++mt)
                    #pragma unroll
                    for (int nt = 0; nt < 4; ++nt)
                        acc[mt][nt] = __builtin_amdgcn_mfma_f32_16x16x32_f16(
                            af[mt], bf[nt], acc[mt][nt], 0, 0, 0);
            }
        }
        // scores; running top-2 per token row (this lane's column stream)
        #pragma unroll
        for (int nt = 0; nt < 4; ++nt) {
            const int col = ct * 128 + chh * 64 + nt * 16 + m;
            #pragma unroll
            for (int mt = 0; mt < 2; ++mt)
                #pragma unroll
                for (int r = 0; r < 4; ++r) {
                    float s = fmaf(NEG2_SCALE, acc[mt][nt][r], w2c[nt]);
                    const int ri = mt * 4 + r;
                    if (s < b1[ri]) { b2[ri] = b1[ri]; b1[ri] = s; i1[ri] = col; }
                    else if (s < b2[ri]) b2[ri] = s;
                }
        }
    }

    // merge across the 16 m-lanes (top-2, ties -> smaller k)
    #pragma unroll
    for (int msk = 1; msk < 16; msk <<= 1) {
        #pragma unroll
        for (int ri = 0; ri < 8; ++ri) {
            float o1 = __shfl_xor(b1[ri], msk, 64);
            int   oi = __shfl_xor(i1[ri], msk, 64);
            float o2 = __shfl_xor(b2[ri], msk, 64);
            if (o1 < b1[ri] || (o1 == b1[ri] && oi < i1[ri])) {
                b2[ri] = fminf(b1[ri], o2); b1[ri] = o1; i1[ri] = oi;
            } else {
                b2[ri] = fminf(b2[ri], o1);
            }
        }
    }

    // cross code-half merge via LDS (reuse As)
    __syncthreads();
    float* Lb1 = (float*)As;
    float* Lb2 = Lb1 + 64;
    int*   Li  = (int*)(Lb1 + 128);
    if (chh == 1 && m == 0) {
        #pragma unroll
        for (int ri = 0; ri < 8; ++ri) {
            int row = rh * 32 + (ri >> 2) * 16 + quad * 4 + (ri & 3);
            Lb1[row] = b1[ri]; Lb2[row] = b2[ri]; Li[row] = i1[ri];
        }
    }
    __syncthreads();
    if (chh == 0 && m == 0) {
        #pragma unroll
        for (int ri = 0; ri < 8; ++ri) {
            int row = rh * 32 + (ri >> 2) * 16 + quad * 4 + (ri & 3);
            float o1 = Lb1[row], o2 = Lb2[row]; int oi = Li[row];
            if (o1 < b1[ri] || (o1 == b1[ri] && oi < i1[ri])) {
                b2[ri] = fminf(b1[ri], o2); b1[ri] = o1; i1[ri] = oi;
            } else {
                b2[ri] = fminf(b2[ri], o1);
            }
            int tok = tok0 + row;
            out_idx_f[tok] = (float)i1[ri];
            if (b2[ri] - b1[ri] <= TAU) {
                int p = atomicAdd(cnt, 1);
                list[p] = tok;
            }
        }
    }
}

// ---------- exact np-emulating recheck, 4 rows per block (round-3-validated) ----------
__global__ __launch_bounds__(256) void recheck_kernel(
    const float* __restrict__ z, const float* __restrict__ cb,
    const float* __restrict__ w2, const int* __restrict__ cnt,
    const int* __restrict__ list, float* __restrict__ out_idx_f)
{
    __shared__ float zrow[4][DIMD];
    __shared__ float z2s[4];
    __shared__ float rv[4][4];
    __shared__ int   ri[4][4];

    const int tid  = threadIdx.x;
    const int wave = tid >> 6;
    const int lane = tid & 63;
    const int total = *cnt;
    const int ngrp = (total + 3) >> 2;

    for (int g = blockIdx.x; g < ngrp; g += gridDim.x) {
        __syncthreads();
        const int nrows = min(4, total - g * 4);
        {
            int idx = g * 4 + wave;
            int tok = (idx < total) ? list[idx] : list[g * 4];
            int b = tok >> 11, t = tok & 2047;
            const float* zb = z + (size_t)b * DIMD * TT + t;
            double zp = 0.0;
            #pragma unroll
            for (int j = 0; j < 8; ++j) {
                int d = lane + 64 * j;
                float v = zb[(size_t)d * TT];
                zrow[wave][d] = v;
                float vv = v * v;
                zp += (double)vv;
            }
            #pragma unroll
            for (int msk = 1; msk < 64; msk <<= 1) zp += __shfl_xor(zp, msk, 64);
            if (lane == 0) z2s[wave] = (float)zp;
        }
        __syncthreads();

        double acc[4][4];
        #pragma unroll
        for (int jc = 0; jc < 4; ++jc)
            #pragma unroll
            for (int r = 0; r < 4; ++r) acc[jc][r] = 0.0;

        for (int d0 = 0; d0 < DIMD; d0 += 4) {
            float4 zv[4];
            #pragma unroll
            for (int r = 0; r < 4; ++r) zv[r] = *(const float4*)&zrow[r][d0];
            #pragma unroll
            for (int jc = 0; jc < 4; ++jc) {
                float4 wv = *(const float4*)(cb + (size_t)(tid + 256 * jc) * DIMD + d0);
                #pragma unroll
                for (int r = 0; r < 4; ++r) {
                    acc[jc][r] = fma((double)zv[r].x, (double)wv.x, acc[jc][r]);
                    acc[jc][r] = fma((double)zv[r].y, (double)wv.y, acc[jc][r]);
                    acc[jc][r] = fma((double)zv[r].z, (double)wv.z, acc[jc][r]);
                    acc[jc][r] = fma((double)zv[r].w, (double)wv.w, acc[jc][r]);
                }
            }
        }

        float bv[4]; int bi[4];
        #pragma unroll
        for (int r = 0; r < 4; ++r) { bv[r] = 3.4e38f; bi[r] = 0; }
        #pragma unroll
        for (int jc = 0; jc < 4; ++jc) {
            int k = tid + 256 * jc;
            float w2k = w2[k];
            #pragma unroll
            for (int r = 0; r < 4; ++r) {
                float dotf = (float)acc[jc][r];
                float t2   = z2s[r] - 2.0f * dotf;
                float s    = t2 + w2k;
                if (s < bv[r] || (s == bv[r] && k < bi[r])) { bv[r] = s; bi[r] = k; }
            }
        }
        #pragma unroll
        for (int msk = 1; msk < 64; msk <<= 1) {
            #pragma unroll
            for (int r = 0; r < 4; ++r) {
                float ov = __shfl_xor(bv[r], msk, 64);
                int   oi = __shfl_xor(bi[r], msk, 64);
                if (ov < bv[r] || (ov == bv[r] && oi < bi[r])) { bv[r] = ov; bi[r] = oi; }
            }
        }
        if (lane == 0) {
            #pragma unroll
            for (int r = 0; r < 4; ++r) { rv[wave][r] = bv[r]; ri[wave][r] = bi[r]; }
        }
        __syncthreads();
        if (tid < nrows) {
            float v = rv[0][tid]; int k = ri[0][tid];
            #pragma unroll
            for (int w = 1; w < 4; ++w) {
                if (rv[w][tid] < v || (rv[w][tid] == v && ri[w][tid] < k)) {
                    v = rv[w][tid]; k = ri[w][tid];
                }
            }
            out_idx_f[list[g * 4 + tid]] = (float)k;
        }
    }
}

// ---------- gather z_q, write z_q_st, accumulate loss ----------
__global__ __launch_bounds__(256) void gather_kernel(
    const float* __restrict__ z, const float* __restrict__ cb,
    const float* __restrict__ idx_f, float* __restrict__ out,
    float* __restrict__ loss)
{
    __shared__ float red[4];
    const size_t base = ((size_t)blockIdx.x * 256 + threadIdx.x) * 4;
    const int t  = (int)(base % TT);
    const int bd = (int)(base / TT);
    const int d  = bd & (DIMD - 1);
    const int b  = bd / DIMD;

    float4 zv = *(const float4*)(z + base);
    const float* ip = idx_f + b * TT + t;
    int k0 = (int)(ip[0] + 0.5f);
    int k1 = (int)(ip[1] + 0.5f);
    int k2 = (int)(ip[2] + 0.5f);
    int k3 = (int)(ip[3] + 0.5f);
    float w0  = cb[(size_t)k0 * DIMD + d];
    float w1  = cb[(size_t)k1 * DIMD + d];
    float w2v = cb[(size_t)k2 * DIMD + d];
    float w3  = cb[(size_t)k3 * DIMD + d];

    float dx = w0 - zv.x, dy = w1 - zv.y, dz = w2v - zv.z, dw = w3 - zv.w;
    float4 ov = make_float4(zv.x + dx, zv.y + dy, zv.z + dz, zv.w + dw);
    *(float4*)(out + base) = ov;

    float part = dx * dx + dy * dy + dz * dz + dw * dw;
    #pragma unroll
    for (int msk = 32; msk >= 1; msk >>= 1) part += __shfl_down(part, msk, 64);
    const int lane = threadIdx.x & 63;
    const int wv   = threadIdx.x >> 6;
    if (lane == 0) red[wv] = part;
    __syncthreads();
    if (threadIdx.x == 0) {
        float tot = red[0] + red[1] + red[2] + red[3];
        atomicAdd(loss, tot * (1.25f / (float)(BB * DIMD * TT)));
    }
}

extern "C" void kernel_launch(void* const* d_in, const int* in_sizes, int n_in,
                              void* d_out, int out_size, void* d_ws, size_t ws_size,
                              hipStream_t stream) {
    const float* z  = (const float*)d_in[0];
    const float* cb = (const float*)d_in[1];
    float* out = (float*)d_out;

    // zf (33.5MB fp16 token-major z) lives in the z_q_st output region,
    // consumed by fast_kernel, then overwritten by gather_kernel.
    f16_t* zf = (f16_t*)out;

    char* wsb = (char*)d_ws;
    f16_t* wf  = (f16_t*)wsb;                       // 1 MB (codebook fp16 x1024)
    float* w2  = (float*)(wsb + (1 << 20));         // 4 KB
    int*   cnt = (int*)(wsb + (1 << 20) + 4096);
    int*   list= (int*)(wsb + (1 << 20) + 8192);    // 128 KB

    hipMemsetAsync(out + OUT_LOSS, 0, sizeof(float), stream);
    hipMemsetAsync(cnt, 0, sizeof(int), stream);
    prep_kernel<<<KCB / 4, 256, 0, stream>>>(cb, wf, w2);
    tsplit_kernel<<<(NTOT / 64) * 4, 256, 0, stream>>>(z, zf);
    fast_kernel<<<NTOT / 64, 256, 0, stream>>>(zf, wf, w2, out + OUT_IDX, cnt, list);
    recheck_kernel<<<512, 256, 0, stream>>>(z, cb, w2, cnt, list, out + OUT_IDX);
    gather_kernel<<<(BB * DIMD * TT) / (256 * 4), 256, 0, stream>>>(
        z, cb, out + OUT_IDX, out, out + OUT_LOSS);
}

// Round 6
// 496.196 us; speedup vs baseline: 3.6366x; 1.2871x over previous
//
#include <hip/hip_runtime.h>

typedef _Float16 f16_t;
typedef _Float16 f16x8 __attribute__((ext_vector_type(8)));
typedef float    f32x4 __attribute__((ext_vector_type(4)));

#define DIMD 512
#define KCB  1024
#define TT   2048
#define BB   16
#define NTOT (BB*TT)                   // 32768
#define OUT_IDX  (BB*DIMD*TT)          // 16777216
#define OUT_LOSS (OUT_IDX + NTOT)
#define TAU 3.0e-4f
// score = w2[k] - 2*dot; fast dot computed on (z, 1024*w) -> scale back by 2^-10
#define NEG2_SCALE (-0.001953125f)     // -2/1024, exact

__device__ __forceinline__ void gll16(const f16_t* g, f16_t* l) {
    __builtin_amdgcn_global_load_lds(
        (const __attribute__((address_space(1))) unsigned int*)g,
        (__attribute__((address_space(3))) unsigned int*)l, 16, 0, 0);
}

// ---------- prep: wf16[k][d] = f16(1024*cb), w2[k] = fl32(fp64 sum fl32(cb^2)) ----------
__global__ __launch_bounds__(256) void prep_kernel(const float* __restrict__ cb,
                                                   f16_t* __restrict__ wf,
                                                   float* __restrict__ w2) {
    const int wave = threadIdx.x >> 6, lane = threadIdx.x & 63;
    const int row  = blockIdx.x * 4 + wave;
    const float* src = cb + (size_t)row * DIMD + lane * 8;
    float4 v0 = *(const float4*)(src);
    float4 v1 = *(const float4*)(src + 4);
    f16x8 o;
    o[0] = (f16_t)(v0.x * 1024.f); o[1] = (f16_t)(v0.y * 1024.f);
    o[2] = (f16_t)(v0.z * 1024.f); o[3] = (f16_t)(v0.w * 1024.f);
    o[4] = (f16_t)(v1.x * 1024.f); o[5] = (f16_t)(v1.y * 1024.f);
    o[6] = (f16_t)(v1.z * 1024.f); o[7] = (f16_t)(v1.w * 1024.f);
    *(f16x8*)(wf + (size_t)row * DIMD + lane * 8) = o;
    float s0 = v0.x * v0.x, s1 = v0.y * v0.y, s2 = v0.z * v0.z, s3 = v0.w * v0.w;
    float s4 = v1.x * v1.x, s5 = v1.y * v1.y, s6 = v1.z * v1.z, s7 = v1.w * v1.w;
    double s = (double)s0 + (double)s1 + (double)s2 + (double)s3 +
               (double)s4 + (double)s5 + (double)s6 + (double)s7;
    #pragma unroll
    for (int m = 1; m < 64; m <<= 1) s += __shfl_xor(s, m, 64);
    if (lane == 0) w2[row] = (float)s;
}

// ---------- transpose z -> token-major fp16; also z2[n] = sum_d z^2 ----------
// block = 64 tokens x full 512 d; wave w covers d in [w*128, w*128+128)
__global__ __launch_bounds__(256) void tsplit_kernel(const float* __restrict__ z,
                                                     f16_t* __restrict__ zf,
                                                     float* __restrict__ z2) {
    __shared__ float zred[4][64];
    const int tid  = threadIdx.x;
    const int wave = tid >> 6, lane = tid & 63;
    const int tok  = blockIdx.x * 64 + lane;
    const int b = tok >> 11, t = tok & 2047;
    const float* src = z + (size_t)b * DIMD * TT + t;
    const int d0 = wave * 128;
    double zp = 0.0;
    for (int j = 0; j < 16; ++j) {
        f16x8 o;
        #pragma unroll
        for (int u = 0; u < 8; ++u) {
            float v = src[(size_t)(d0 + j * 8 + u) * TT];
            o[u] = (f16_t)v;
            float vv = v * v;
            zp += (double)vv;
        }
        *(f16x8*)(zf + (size_t)tok * DIMD + d0 + j * 8) = o;
    }
    zred[wave][lane] = (float)zp;
    __syncthreads();
    if (wave == 0)
        z2[blockIdx.x * 64 + lane] =
            zred[0][lane] + zred[1][lane] + zred[2][lane] + zred[3][lane];
}

// ---------- fast argmin: fp16 MFMA, XOR-swizzled LDS, 64tok x 1024codes ----------
__global__ __launch_bounds__(256, 4) void fast_kernel(
    const f16_t* __restrict__ zf, const f16_t* __restrict__ wf,
    const float* __restrict__ w2, float* __restrict__ out_idx_f,
    float* __restrict__ score, int* __restrict__ cnt, int* __restrict__ list)
{
    __shared__ __align__(16) f16_t As[64 * 64];    // 8KB  [tok][d] swizzled
    __shared__ __align__(16) f16_t Bs[128 * 64];   // 16KB [code][d] swizzled

    const int tid  = threadIdx.x;
    const int wave = tid >> 6;
    const int lane = tid & 63;
    const int m    = lane & 15;
    const int quad = lane >> 4;
    const int rh   = wave & 1;     // token half (32)
    const int chh  = wave >> 1;    // code half (64)
    const int tok0 = blockIdx.x * 64;

    const f16_t* gA[2]; f16_t* lA[2];
    const f16_t* gB[4]; f16_t* lB[4];
    #pragma unroll
    for (int q = 0; q < 2; ++q) {
        int s = q * 256 + tid, row = s >> 3, p = s & 7, gc = p ^ (row & 7);
        gA[q] = zf + (size_t)(tok0 + row) * DIMD + gc * 8;
        lA[q] = As + s * 8;
    }
    #pragma unroll
    for (int q = 0; q < 4; ++q) {
        int s = q * 256 + tid, row = s >> 3, p = s & 7, gc = p ^ (row & 7);
        gB[q] = wf + (size_t)row * DIMD + gc * 8;
        lB[q] = Bs + s * 8;
    }

    float b1[8], b2[8]; int i1[8];
    #pragma unroll
    for (int r = 0; r < 8; ++r) { b1[r] = 3.4e38f; b2[r] = 3.4e38f; i1[r] = 0; }

    const int xorm = m & 7;
    for (int ct = 0; ct < 8; ++ct) {
        float w2c[4];
        #pragma unroll
        for (int nt = 0; nt < 4; ++nt)
            w2c[nt] = w2[ct * 128 + chh * 64 + nt * 16 + m];

        f32x4 acc[2][4] = {};
        const size_t ctoff = (size_t)ct * 128 * DIMD;
        for (int d0 = 0; d0 < DIMD; d0 += 64) {
            __syncthreads();
            #pragma unroll
            for (int q = 0; q < 2; ++q) gll16(gA[q] + d0, lA[q]);
            #pragma unroll
            for (int q = 0; q < 4; ++q) gll16(gB[q] + ctoff + d0, lB[q]);
            __syncthreads();
            #pragma unroll
            for (int kh = 0; kh < 2; ++kh) {
                const int csw = ((kh * 4 + quad) ^ xorm) * 8;
                f16x8 af[2], bf[4];
                #pragma unroll
                for (int mt = 0; mt < 2; ++mt)
                    af[mt] = *(const f16x8*)(As + (rh * 32 + mt * 16 + m) * 64 + csw);
                #pragma unroll
                for (int nt = 0; nt < 4; ++nt)
                    bf[nt] = *(const f16x8*)(Bs + (chh * 64 + nt * 16 + m) * 64 + csw);
                #pragma unroll
                for (int mt = 0; mt < 2; ++mt)
                    #pragma unroll
                    for (int nt = 0; nt < 4; ++nt)
                        acc[mt][nt] = __builtin_amdgcn_mfma_f32_16x16x32_f16(
                            af[mt], bf[nt], acc[mt][nt], 0, 0, 0);
            }
        }
        #pragma unroll
        for (int nt = 0; nt < 4; ++nt) {
            const int col = ct * 128 + chh * 64 + nt * 16 + m;
            #pragma unroll
            for (int mt = 0; mt < 2; ++mt)
                #pragma unroll
                for (int r = 0; r < 4; ++r) {
                    float s = fmaf(NEG2_SCALE, acc[mt][nt][r], w2c[nt]);
                    const int ri = mt * 4 + r;
                    if (s < b1[ri]) { b2[ri] = b1[ri]; b1[ri] = s; i1[ri] = col; }
                    else if (s < b2[ri]) b2[ri] = s;
                }
        }
    }

    #pragma unroll
    for (int msk = 1; msk < 16; msk <<= 1) {
        #pragma unroll
        for (int ri = 0; ri < 8; ++ri) {
            float o1 = __shfl_xor(b1[ri], msk, 64);
            int   oi = __shfl_xor(i1[ri], msk, 64);
            float o2 = __shfl_xor(b2[ri], msk, 64);
            if (o1 < b1[ri] || (o1 == b1[ri] && oi < i1[ri])) {
                b2[ri] = fminf(b1[ri], o2); b1[ri] = o1; i1[ri] = oi;
            } else {
                b2[ri] = fminf(b2[ri], o1);
            }
        }
    }

    __syncthreads();
    float* Lb1 = (float*)As;
    float* Lb2 = Lb1 + 64;
    int*   Li  = (int*)(Lb1 + 128);
    if (chh == 1 && m == 0) {
        #pragma unroll
        for (int ri = 0; ri < 8; ++ri) {
            int row = rh * 32 + (ri >> 2) * 16 + quad * 4 + (ri & 3);
            Lb1[row] = b1[ri]; Lb2[row] = b2[ri]; Li[row] = i1[ri];
        }
    }
    __syncthreads();
    if (chh == 0 && m == 0) {
        #pragma unroll
        for (int ri = 0; ri < 8; ++ri) {
            int row = rh * 32 + (ri >> 2) * 16 + quad * 4 + (ri & 3);
            float o1 = Lb1[row], o2 = Lb2[row]; int oi = Li[row];
            if (o1 < b1[ri] || (o1 == b1[ri] && oi < i1[ri])) {
                b2[ri] = fminf(b1[ri], o2); b1[ri] = o1; i1[ri] = oi;
            } else {
                b2[ri] = fminf(b2[ri], o1);
            }
            int tok = tok0 + row;
            out_idx_f[tok] = (float)i1[ri];
            score[tok] = b1[ri];           // w2[k*] - 2*dot  (loss term)
            if (b2[ri] - b1[ri] <= TAU) {
                int p = atomicAdd(cnt, 1);
                list[p] = tok;
            }
        }
    }
}

// ---------- exact np-emulating recheck, 4 rows per block (round-3-validated) ----------
// (indices only; score left stale — contributes < 1e-7 to the loss)
__global__ __launch_bounds__(256) void recheck_kernel(
    const float* __restrict__ z, const float* __restrict__ cb,
    const float* __restrict__ w2, const int* __restrict__ cnt,
    const int* __restrict__ list, float* __restrict__ out_idx_f)
{
    __shared__ float zrow[4][DIMD];
    __shared__ float z2s[4];
    __shared__ float rv[4][4];
    __shared__ int   ri[4][4];

    const int tid  = threadIdx.x;
    const int wave = tid >> 6;
    const int lane = tid & 63;
    const int total = *cnt;
    const int ngrp = (total + 3) >> 2;

    for (int g = blockIdx.x; g < ngrp; g += gridDim.x) {
        __syncthreads();
        const int nrows = min(4, total - g * 4);
        {
            int idx = g * 4 + wave;
            int tok = (idx < total) ? list[idx] : list[g * 4];
            int b = tok >> 11, t = tok & 2047;
            const float* zb = z + (size_t)b * DIMD * TT + t;
            double zp = 0.0;
            #pragma unroll
            for (int j = 0; j < 8; ++j) {
                int d = lane + 64 * j;
                float v = zb[(size_t)d * TT];
                zrow[wave][d] = v;
                float vv = v * v;
                zp += (double)vv;
            }
            #pragma unroll
            for (int msk = 1; msk < 64; msk <<= 1) zp += __shfl_xor(zp, msk, 64);
            if (lane == 0) z2s[wave] = (float)zp;
        }
        __syncthreads();

        double acc[4][4];
        #pragma unroll
        for (int jc = 0; jc < 4; ++jc)
            #pragma unroll
            for (int r = 0; r < 4; ++r) acc[jc][r] = 0.0;

        for (int d0 = 0; d0 < DIMD; d0 += 4) {
            float4 zv[4];
            #pragma unroll
            for (int r = 0; r < 4; ++r) zv[r] = *(const float4*)&zrow[r][d0];
            #pragma unroll
            for (int jc = 0; jc < 4; ++jc) {
                float4 wv = *(const float4*)(cb + (size_t)(tid + 256 * jc) * DIMD + d0);
                #pragma unroll
                for (int r = 0; r < 4; ++r) {
                    acc[jc][r] = fma((double)zv[r].x, (double)wv.x, acc[jc][r]);
                    acc[jc][r] = fma((double)zv[r].y, (double)wv.y, acc[jc][r]);
                    acc[jc][r] = fma((double)zv[r].z, (double)wv.z, acc[jc][r]);
                    acc[jc][r] = fma((double)zv[r].w, (double)wv.w, acc[jc][r]);
                }
            }
        }

        float bv[4]; int bi[4];
        #pragma unroll
        for (int r = 0; r < 4; ++r) { bv[r] = 3.4e38f; bi[r] = 0; }
        #pragma unroll
        for (int jc = 0; jc < 4; ++jc) {
            int k = tid + 256 * jc;
            float w2k = w2[k];
            #pragma unroll
            for (int r = 0; r < 4; ++r) {
                float dotf = (float)acc[jc][r];
                float t2   = z2s[r] - 2.0f * dotf;
                float s    = t2 + w2k;
                if (s < bv[r] || (s == bv[r] && k < bi[r])) { bv[r] = s; bi[r] = k; }
            }
        }
        #pragma unroll
        for (int msk = 1; msk < 64; msk <<= 1) {
            #pragma unroll
            for (int r = 0; r < 4; ++r) {
                float ov = __shfl_xor(bv[r], msk, 64);
                int   oi = __shfl_xor(bi[r], msk, 64);
                if (ov < bv[r] || (ov == bv[r] && oi < bi[r])) { bv[r] = ov; bi[r] = oi; }
            }
        }
        if (lane == 0) {
            #pragma unroll
            for (int r = 0; r < 4; ++r) { rv[wave][r] = bv[r]; ri[wave][r] = bi[r]; }
        }
        __syncthreads();
        if (tid < nrows) {
            float v = rv[0][tid]; int k = ri[0][tid];
            #pragma unroll
            for (int w = 1; w < 4; ++w) {
                if (rv[w][tid] < v || (rv[w][tid] == v && ri[w][tid] < k)) {
                    v = rv[w][tid]; k = ri[w][tid];
                }
            }
            out_idx_f[list[g * 4 + tid]] = (float)k;
        }
    }
}

// ---------- pure gather: out = codebook[idx]  (z_q_st forward value == z_q) ----------
__global__ __launch_bounds__(256) void gather_kernel(
    const float* __restrict__ cb, const float* __restrict__ idx_f,
    float* __restrict__ out)
{
    const size_t base = ((size_t)blockIdx.x * 256 + threadIdx.x) * 4;
    const int t  = (int)(base % TT);
    const int bd = (int)(base / TT);
    const int d  = bd & (DIMD - 1);
    const int b  = bd >> 9;

    const float* ip = idx_f + b * TT + t;
    int k0 = (int)(ip[0] + 0.5f);
    int k1 = (int)(ip[1] + 0.5f);
    int k2 = (int)(ip[2] + 0.5f);
    int k3 = (int)(ip[3] + 0.5f);
    float4 ov = make_float4(cb[(size_t)k0 * DIMD + d],
                            cb[(size_t)k1 * DIMD + d],
                            cb[(size_t)k2 * DIMD + d],
                            cb[(size_t)k3 * DIMD + d]);
    *(float4*)(out + base) = ov;
}

// ---------- loss = 1.25/(N*D) * sum_n (z2[n] + score[n]) ----------
__global__ __launch_bounds__(256) void loss_kernel(const float* __restrict__ z2,
                                                   const float* __restrict__ score,
                                                   float* __restrict__ loss)
{
    __shared__ double red[4];
    const int idx = blockIdx.x * 1024 + threadIdx.x * 4;   // grid 32
    float4 a = *(const float4*)(z2 + idx);
    float4 s = *(const float4*)(score + idx);
    double part = ((double)a.x + (double)s.x) + ((double)a.y + (double)s.y) +
                  ((double)a.z + (double)s.z) + ((double)a.w + (double)s.w);
    #pragma unroll
    for (int m = 1; m < 64; m <<= 1) part += __shfl_xor(part, m, 64);
    const int lane = threadIdx.x & 63, wv = threadIdx.x >> 6;
    if (lane == 0) red[wv] = part;
    __syncthreads();
    if (threadIdx.x == 0) {
        double tot = red[0] + red[1] + red[2] + red[3];
        atomicAdd(loss, (float)(tot * (1.25 / (double)(BB * DIMD * TT))));
    }
}

extern "C" void kernel_launch(void* const* d_in, const int* in_sizes, int n_in,
                              void* d_out, int out_size, void* d_ws, size_t ws_size,
                              hipStream_t stream) {
    const float* z  = (const float*)d_in[0];
    const float* cb = (const float*)d_in[1];
    float* out = (float*)d_out;

    // zf (33.5MB fp16 token-major z) lives in the z_q_st output region,
    // consumed by fast_kernel, then overwritten by gather_kernel.
    f16_t* zf = (f16_t*)out;

    char* wsb = (char*)d_ws;
    f16_t* wf    = (f16_t*)wsb;                         // 1 MB
    float* w2    = (float*)(wsb + (1 << 20));           // 4 KB
    int*   cnt   = (int*)(wsb + (1 << 20) + 4096);
    int*   list  = (int*)(wsb + (1 << 20) + 8192);      // 128 KB
    float* z2    = (float*)(wsb + (1 << 20) + 8192 + (128 << 10));   // 128 KB
    float* score = z2 + NTOT;                           // 128 KB

    hipMemsetAsync(out + OUT_LOSS, 0, sizeof(float), stream);
    hipMemsetAsync(cnt, 0, sizeof(int), stream);
    prep_kernel<<<KCB / 4, 256, 0, stream>>>(cb, wf, w2);
    tsplit_kernel<<<NTOT / 64, 256, 0, stream>>>(z, zf, z2);
    fast_kernel<<<NTOT / 64, 256, 0, stream>>>(zf, wf, w2, out + OUT_IDX, score, cnt, list);
    recheck_kernel<<<512, 256, 0, stream>>>(z, cb, w2, cnt, list, out + OUT_IDX);
    gather_kernel<<<(BB * DIMD * TT) / (256 * 4), 256, 0, stream>>>(
        cb, out + OUT_IDX, out);
    loss_kernel<<<NTOT / 1024, 256, 0, stream>>>(z2, score, out + OUT_LOSS);
}